// Round 4
// baseline (352.986 us; speedup 1.0000x reference)
//
#include <hip/hip_runtime.h>
#include <math.h>

// ---- pass1 geometry ------------------------------------------------------
// NB1 * BS * LQ * NBATCH float4s == N/4 == 2^23  (2048*256*4*4 = 8388608)
#define NB1 2048     // grid
#define BS 256       // block size (4 waves)
#define LQ 4         // float4 (and int4) loads per batch per thread
#define NBATCH 4     // batches per thread (software-pipelined)

typedef float __attribute__((ext_vector_type(4))) vfloat4;
typedef int   __attribute__((ext_vector_type(4))) vint4;

// Opaque non-temporal 16B loads. Measured ladder on this problem:
// NT-reg 3.78 TB/s > cached 3.0 > global_load_lds DMA 2.53. Reads are
// capped by per-CU outstanding-request capacity (~210 lines ~= 15 GB/s/CU
// at ~900ns), so NT-reg is the ceiling path; keep it.
__device__ __forceinline__ void ld_nt_f4(const vfloat4* p, vfloat4& d) {
    asm volatile("global_load_dwordx4 %0, %1, off nt" : "=v"(d) : "v"(p));
}
__device__ __forceinline__ void ld_nt_i4(const vint4* p, vint4& d) {
    asm volatile("global_load_dwordx4 %0, %1, off nt" : "=v"(d) : "v"(p));
}

#define ISSUE(R0, R1, R2, R3, W0, W1, W2, W3, t)                    \
    do {                                                            \
        const vfloat4* _px = x4 + base0 + (t) * (LQ * BS);          \
        const vint4*   _py = y4 + base0 + (t) * (LQ * BS);          \
        ld_nt_f4(_px + 0 * BS, R0);                                 \
        ld_nt_f4(_px + 1 * BS, R1);                                 \
        ld_nt_f4(_px + 2 * BS, R2);                                 \
        ld_nt_f4(_px + 3 * BS, R3);                                 \
        ld_nt_i4(_py + 0 * BS, W0);                                 \
        ld_nt_i4(_py + 1 * BS, W1);                                 \
        ld_nt_i4(_py + 2 * BS, W2);                                 \
        ld_nt_i4(_py + 3 * BS, W3);                                 \
    } while (0)

// Counted wait: the 8 newest loads (next batch) stay in flight across the
// consume phase -- vmcnt never drains to 0 inside the pipeline.
#define WAIT_PREV(R0, R1, R2, R3, W0, W1, W2, W3)                   \
    asm volatile("s_waitcnt vmcnt(8)"                               \
                 : "+v"(R0), "+v"(R1), "+v"(R2), "+v"(R3),          \
                   "+v"(W0), "+v"(W1), "+v"(W2), "+v"(W3))

#define WAIT_LAST(R0, R1, R2, R3, W0, W1, W2, W3)                   \
    asm volatile("s_waitcnt vmcnt(0)"                               \
                 : "+v"(R0), "+v"(R1), "+v"(R2), "+v"(R3),          \
                   "+v"(W0), "+v"(W1), "+v"(W2), "+v"(W3))

__device__ __forceinline__ void consume(vfloat4 v0, vfloat4 v1, vfloat4 v2, vfloat4 v3,
                                        vint4 w0, vint4 w1, vint4 w2, vint4 w3,
                                        double& sum, double& sum0, int& cnt0,
                                        float& mn, float& mx) {
    float fs[LQ], ft[LQ], fmn[LQ], fmx[LQ];
    int   fc[LQ];
    const vfloat4 vv[LQ] = {v0, v1, v2, v3};
    const vint4   ww[LQ] = {w0, w1, w2, w3};
    #pragma unroll
    for (int q = 0; q < LQ; ++q) {
        vfloat4 v = vv[q];
        vint4   w = ww[q];
        fs[q] = (v.x + v.y) + (v.z + v.w);
        float a  = (w.x == 0) ? v.x : 0.0f;
        float b  = (w.y == 0) ? v.y : 0.0f;
        float cc = (w.z == 0) ? v.z : 0.0f;
        float d  = (w.w == 0) ? v.w : 0.0f;
        ft[q] = (a + b) + (cc + d);
        fc[q] = (w.x == 0) + (w.y == 0) + (w.z == 0) + (w.w == 0);
        fmn[q] = fminf(fminf(v.x, v.y), fminf(v.z, v.w));
        fmx[q] = fmaxf(fmaxf(v.x, v.y), fmaxf(v.z, v.w));
    }
    float sA = (fs[0] + fs[1]) + (fs[2] + fs[3]);
    float tA = (ft[0] + ft[1]) + (ft[2] + ft[3]);
    sum  += (double)sA;
    sum0 += (double)tA;
    cnt0 += (fc[0] + fc[1]) + (fc[2] + fc[3]);
    mn = fminf(mn, fminf(fminf(fmn[0], fmn[1]), fminf(fmn[2], fmn[3])));
    mx = fmaxf(mx, fmaxf(fmaxf(fmx[0], fmx[1]), fmaxf(fmx[2], fmx[3])));
}

// ws layout (doubles, stride NB1): [0) sum_all [1) sum0 [2) cnt0 [3) min [4) max
// counter: one uint at byte offset 5*NB1*8 (zeroed by in-graph memsetAsync).

__global__ __launch_bounds__(BS) void risk_pass1(const float* __restrict__ x,
                                                 const int* __restrict__ y,
                                                 double* __restrict__ ws,
                                                 unsigned int* __restrict__ cnt,
                                                 float* __restrict__ out,
                                                 long long n_total) {
    const vfloat4* __restrict__ x4 = (const vfloat4*)x;
    const vint4*   __restrict__ y4 = (const vint4*)y;

    const int base0 = blockIdx.x * (NBATCH * LQ * BS) + threadIdx.x;

    vfloat4 a0, a1, a2, a3;  vint4 b0, b1, b2, b3;   // register set A
    vfloat4 c0, c1, c2, c3;  vint4 d0, d1, d2, d3;   // register set B

    double sum = 0.0, sum0 = 0.0;
    int    cnt0 = 0;
    float  mn =  INFINITY, mx = -INFINITY;

    // Software pipeline: issue t+1, wait vmcnt(8) for t, consume t.
    ISSUE(a0, a1, a2, a3, b0, b1, b2, b3, 0);

    ISSUE(c0, c1, c2, c3, d0, d1, d2, d3, 1);
    WAIT_PREV(a0, a1, a2, a3, b0, b1, b2, b3);
    consume(a0, a1, a2, a3, b0, b1, b2, b3, sum, sum0, cnt0, mn, mx);

    ISSUE(a0, a1, a2, a3, b0, b1, b2, b3, 2);
    WAIT_PREV(c0, c1, c2, c3, d0, d1, d2, d3);
    consume(c0, c1, c2, c3, d0, d1, d2, d3, sum, sum0, cnt0, mn, mx);

    ISSUE(c0, c1, c2, c3, d0, d1, d2, d3, 3);
    WAIT_PREV(a0, a1, a2, a3, b0, b1, b2, b3);
    consume(a0, a1, a2, a3, b0, b1, b2, b3, sum, sum0, cnt0, mn, mx);

    WAIT_LAST(c0, c1, c2, c3, d0, d1, d2, d3);
    consume(c0, c1, c2, c3, d0, d1, d2, d3, sum, sum0, cnt0, mn, mx);

    // wave (64-lane) reduction
    for (int off = 32; off > 0; off >>= 1) {
        sum  += __shfl_down(sum,  off);
        sum0 += __shfl_down(sum0, off);
        cnt0 += __shfl_down(cnt0, off);
        mn = fminf(mn, __shfl_down(mn, off));
        mx = fmaxf(mx, __shfl_down(mx, off));
    }

    __shared__ double s_sum[BS / 64], s_sum0[BS / 64];
    __shared__ int    s_cnt[BS / 64];
    __shared__ float  s_mn[BS / 64], s_mx[BS / 64];
    __shared__ int    s_last;

    int lane = threadIdx.x & 63;
    int wave = threadIdx.x >> 6;
    if (lane == 0) {
        s_sum[wave] = sum; s_sum0[wave] = sum0; s_cnt[wave] = cnt0;
        s_mn[wave] = mn; s_mx[wave] = mx;
    }
    __syncthreads();

    if (threadIdx.x == 0) {
        double bsum = s_sum[0], bsum0 = s_sum0[0];
        int bcnt = s_cnt[0];
        float bmn = s_mn[0], bmx = s_mx[0];
        #pragma unroll
        for (int w = 1; w < BS / 64; ++w) {
            bsum += s_sum[w]; bsum0 += s_sum0[w]; bcnt += s_cnt[w];
            bmn = fminf(bmn, s_mn[w]); bmx = fmaxf(bmx, s_mx[w]);
        }
        // Publish partials with agent-scope atomic stores (per-XCD L2s are
        // not cross-coherent; the release RMW below + these being atomics
        // makes them visible to the finalizing block on any XCD).
        __hip_atomic_store(&ws[0 * NB1 + blockIdx.x], bsum,         __ATOMIC_RELAXED, __HIP_MEMORY_SCOPE_AGENT);
        __hip_atomic_store(&ws[1 * NB1 + blockIdx.x], bsum0,        __ATOMIC_RELAXED, __HIP_MEMORY_SCOPE_AGENT);
        __hip_atomic_store(&ws[2 * NB1 + blockIdx.x], (double)bcnt, __ATOMIC_RELAXED, __HIP_MEMORY_SCOPE_AGENT);
        __hip_atomic_store(&ws[3 * NB1 + blockIdx.x], (double)bmn,  __ATOMIC_RELAXED, __HIP_MEMORY_SCOPE_AGENT);
        __hip_atomic_store(&ws[4 * NB1 + blockIdx.x], (double)bmx,  __ATOMIC_RELAXED, __HIP_MEMORY_SCOPE_AGENT);
        unsigned int old = __hip_atomic_fetch_add(cnt, 1u, __ATOMIC_ACQ_REL, __HIP_MEMORY_SCOPE_AGENT);
        s_last = (old == NB1 - 1);
    }
    __syncthreads();

    if (!s_last) return;

    // ---- finalize (last-arriving block only) -----------------------------
    double fsum = 0.0, fsum0 = 0.0, fcnt = 0.0;
    double fmnd =  INFINITY, fmxd = -INFINITY;
    for (int i = threadIdx.x; i < NB1; i += BS) {
        fsum  += __hip_atomic_load(&ws[0 * NB1 + i], __ATOMIC_RELAXED, __HIP_MEMORY_SCOPE_AGENT);
        fsum0 += __hip_atomic_load(&ws[1 * NB1 + i], __ATOMIC_RELAXED, __HIP_MEMORY_SCOPE_AGENT);
        fcnt  += __hip_atomic_load(&ws[2 * NB1 + i], __ATOMIC_RELAXED, __HIP_MEMORY_SCOPE_AGENT);
        fmnd = fmin(fmnd, __hip_atomic_load(&ws[3 * NB1 + i], __ATOMIC_RELAXED, __HIP_MEMORY_SCOPE_AGENT));
        fmxd = fmax(fmxd, __hip_atomic_load(&ws[4 * NB1 + i], __ATOMIC_RELAXED, __HIP_MEMORY_SCOPE_AGENT));
    }

    for (int off = 32; off > 0; off >>= 1) {
        fsum  += __shfl_down(fsum,  off);
        fsum0 += __shfl_down(fsum0, off);
        fcnt  += __shfl_down(fcnt,  off);
        fmnd = fmin(fmnd, __shfl_down(fmnd, off));
        fmxd = fmax(fmxd, __shfl_down(fmxd, off));
    }

    __shared__ double f_sum[BS / 64], f_sum0[BS / 64], f_cnt[BS / 64];
    __shared__ double f_mn[BS / 64], f_mx[BS / 64];
    if (lane == 0) {
        f_sum[wave] = fsum; f_sum0[wave] = fsum0; f_cnt[wave] = fcnt;
        f_mn[wave] = fmnd; f_mx[wave] = fmxd;
    }
    __syncthreads();

    if (threadIdx.x == 0) {
        double tsum = f_sum[0], tsum0 = f_sum0[0], tcnt0 = f_cnt[0];
        double tmn = f_mn[0], tmx = f_mx[0];
        #pragma unroll
        for (int w = 1; w < BS / 64; ++w) {
            tsum += f_sum[w]; tsum0 += f_sum0[w]; tcnt0 += f_cnt[w];
            tmn = fmin(tmn, f_mn[w]); tmx = fmax(tmx, f_mx[w]);
        }
        double range = tmx - tmn;
        double n1 = (double)n_total - tcnt0;
        double sum1 = tsum - tsum0;
        double m0 = (tsum0 / tcnt0 - tmn) / range;
        double m1 = (sum1  / n1    - tmn) / range;
        double l = fmin(m0, m1) - fmax(m0, m1);  // = -|m0 - m1|
        out[0] = (float)l;
    }
}

extern "C" void kernel_launch(void* const* d_in, const int* in_sizes, int n_in,
                              void* d_out, int out_size, void* d_ws, size_t ws_size,
                              hipStream_t stream) {
    const float* x = (const float*)d_in[0];
    const int*   y = (const int*)d_in[1];
    float* out = (float*)d_out;
    double* ws = (double*)d_ws;
    unsigned int* cnt = (unsigned int*)((char*)d_ws + 5 * NB1 * sizeof(double));
    long long n = (long long)in_sizes[0];  // 33554432 == NB1*BS*LQ*NBATCH*4

    // Zero the completion counter in-graph (workspace is poisoned each replay).
    hipMemsetAsync(cnt, 0, sizeof(unsigned int), stream);
    risk_pass1<<<NB1, BS, 0, stream>>>(x, y, ws, cnt, out, n);
}

// Round 5
// 250.095 us; speedup vs baseline: 1.4114x; 1.4114x over previous
//
#include <hip/hip_runtime.h>
#include <math.h>

// ---- pass1 geometry ------------------------------------------------------
// NB1 * BS * LQ * NBATCH float4s == N/4 == 2^23  (2048*256*4*4 = 8388608)
#define NB1 2048     // pass1 grid
#define BS 256       // pass1 block size (4 waves)
#define LQ 4         // float4 (and int4) loads per batch per thread
#define NBATCH 4     // batches per thread (software-pipelined)
#define P2BS 512     // pass2 block size

typedef float __attribute__((ext_vector_type(4))) vfloat4;
typedef int   __attribute__((ext_vector_type(4))) vint4;

// Opaque non-temporal 16B loads. Measured ladder on this problem:
// NT-reg 3.78 TB/s > mixed-cached 3.0 > global_load_lds DMA 2.53 TB/s.
// Reads are capped by per-CU outstanding-request bookkeeping (~14 KB/CU
// effective in flight at ~900 ns), independent of cache policy and of
// whether lines hit MALL (R4: FETCH=128 MiB MALL-resident, same 3.78).
// Fused single-kernel finalize regresses (R4: per-block agent-scope
// ACQ_REL -> 2048x buffer_wbl2/buffer_inv L2 storms, pass1 71->150 us).
__device__ __forceinline__ void ld_nt_f4(const vfloat4* p, vfloat4& d) {
    asm volatile("global_load_dwordx4 %0, %1, off nt" : "=v"(d) : "v"(p));
}
__device__ __forceinline__ void ld_nt_i4(const vint4* p, vint4& d) {
    asm volatile("global_load_dwordx4 %0, %1, off nt" : "=v"(d) : "v"(p));
}

// Issue one batch: 4 x-loads + 4 y-loads (8 KB/wave in flight).
#define ISSUE(R0, R1, R2, R3, W0, W1, W2, W3, t)                    \
    do {                                                            \
        const vfloat4* _px = x4 + base0 + (t) * (LQ * BS);          \
        const vint4*   _py = y4 + base0 + (t) * (LQ * BS);          \
        ld_nt_f4(_px + 0 * BS, R0);                                 \
        ld_nt_f4(_px + 1 * BS, R1);                                 \
        ld_nt_f4(_px + 2 * BS, R2);                                 \
        ld_nt_f4(_px + 3 * BS, R3);                                 \
        ld_nt_i4(_py + 0 * BS, W0);                                 \
        ld_nt_i4(_py + 1 * BS, W1);                                 \
        ld_nt_i4(_py + 2 * BS, W2);                                 \
        ld_nt_i4(_py + 3 * BS, W3);                                 \
    } while (0)

// Counted wait: the 8 newest loads (next batch) stay in flight across the
// consume phase -- vmcnt never drains to 0 inside the pipeline.
#define WAIT_PREV(R0, R1, R2, R3, W0, W1, W2, W3)                   \
    asm volatile("s_waitcnt vmcnt(8)"                               \
                 : "+v"(R0), "+v"(R1), "+v"(R2), "+v"(R3),          \
                   "+v"(W0), "+v"(W1), "+v"(W2), "+v"(W3))

#define WAIT_LAST(R0, R1, R2, R3, W0, W1, W2, W3)                   \
    asm volatile("s_waitcnt vmcnt(0)"                               \
                 : "+v"(R0), "+v"(R1), "+v"(R2), "+v"(R3),          \
                   "+v"(W0), "+v"(W1), "+v"(W2), "+v"(W3))

// Accumulate one batch (16 floats + 16 labels) into running stats.
// fp32 pairwise tree per batch, one f64 promotion per batch per stat.
__device__ __forceinline__ void consume(vfloat4 v0, vfloat4 v1, vfloat4 v2, vfloat4 v3,
                                        vint4 w0, vint4 w1, vint4 w2, vint4 w3,
                                        double& sum, double& sum0, int& cnt0,
                                        float& mn, float& mx) {
    float fs[LQ], ft[LQ], fmn[LQ], fmx[LQ];
    int   fc[LQ];
    const vfloat4 vv[LQ] = {v0, v1, v2, v3};
    const vint4   ww[LQ] = {w0, w1, w2, w3};
    #pragma unroll
    for (int q = 0; q < LQ; ++q) {
        vfloat4 v = vv[q];
        vint4   w = ww[q];
        fs[q] = (v.x + v.y) + (v.z + v.w);
        float a  = (w.x == 0) ? v.x : 0.0f;
        float b  = (w.y == 0) ? v.y : 0.0f;
        float cc = (w.z == 0) ? v.z : 0.0f;
        float d  = (w.w == 0) ? v.w : 0.0f;
        ft[q] = (a + b) + (cc + d);
        fc[q] = (w.x == 0) + (w.y == 0) + (w.z == 0) + (w.w == 0);
        fmn[q] = fminf(fminf(v.x, v.y), fminf(v.z, v.w));
        fmx[q] = fmaxf(fmaxf(v.x, v.y), fmaxf(v.z, v.w));
    }
    float sA = (fs[0] + fs[1]) + (fs[2] + fs[3]);
    float tA = (ft[0] + ft[1]) + (ft[2] + ft[3]);
    sum  += (double)sA;
    sum0 += (double)tA;
    cnt0 += (fc[0] + fc[1]) + (fc[2] + fc[3]);
    mn = fminf(mn, fminf(fminf(fmn[0], fmn[1]), fminf(fmn[2], fmn[3])));
    mx = fmaxf(mx, fmaxf(fmaxf(fmx[0], fmx[1]), fmaxf(fmx[2], fmx[3])));
}

// Partials layout in d_ws (doubles), stride NB1:
// [0) sum_all  [1) sum0  [2) cnt0  [3) min  [4) max

__global__ __launch_bounds__(BS) void risk_pass1(const float* __restrict__ x,
                                                 const int* __restrict__ y,
                                                 double* __restrict__ ws) {
    const vfloat4* __restrict__ x4 = (const vfloat4*)x;
    const vint4*   __restrict__ y4 = (const vint4*)y;

    // Block b owns the contiguous float4 range [b*NBATCH*LQ*BS, (b+1)*...).
    const int base0 = blockIdx.x * (NBATCH * LQ * BS) + threadIdx.x;

    vfloat4 a0, a1, a2, a3;  vint4 b0, b1, b2, b3;   // register set A
    vfloat4 c0, c1, c2, c3;  vint4 d0, d1, d2, d3;   // register set B

    double sum = 0.0, sum0 = 0.0;
    int    cnt0 = 0;
    float  mn =  INFINITY, mx = -INFINITY;

    // Software pipeline: issue t+1, wait vmcnt(8) for t, consume t.
    ISSUE(a0, a1, a2, a3, b0, b1, b2, b3, 0);

    ISSUE(c0, c1, c2, c3, d0, d1, d2, d3, 1);
    WAIT_PREV(a0, a1, a2, a3, b0, b1, b2, b3);
    consume(a0, a1, a2, a3, b0, b1, b2, b3, sum, sum0, cnt0, mn, mx);

    ISSUE(a0, a1, a2, a3, b0, b1, b2, b3, 2);
    WAIT_PREV(c0, c1, c2, c3, d0, d1, d2, d3);
    consume(c0, c1, c2, c3, d0, d1, d2, d3, sum, sum0, cnt0, mn, mx);

    ISSUE(c0, c1, c2, c3, d0, d1, d2, d3, 3);
    WAIT_PREV(a0, a1, a2, a3, b0, b1, b2, b3);
    consume(a0, a1, a2, a3, b0, b1, b2, b3, sum, sum0, cnt0, mn, mx);

    WAIT_LAST(c0, c1, c2, c3, d0, d1, d2, d3);
    consume(c0, c1, c2, c3, d0, d1, d2, d3, sum, sum0, cnt0, mn, mx);

    // wave (64-lane) reduction
    for (int off = 32; off > 0; off >>= 1) {
        sum  += __shfl_down(sum,  off);
        sum0 += __shfl_down(sum0, off);
        cnt0 += __shfl_down(cnt0, off);
        mn = fminf(mn, __shfl_down(mn, off));
        mx = fmaxf(mx, __shfl_down(mx, off));
    }

    __shared__ double s_sum[BS / 64], s_sum0[BS / 64];
    __shared__ int    s_cnt[BS / 64];
    __shared__ float  s_mn[BS / 64], s_mx[BS / 64];

    int lane = threadIdx.x & 63;
    int wave = threadIdx.x >> 6;
    if (lane == 0) {
        s_sum[wave] = sum; s_sum0[wave] = sum0; s_cnt[wave] = cnt0;
        s_mn[wave] = mn; s_mx[wave] = mx;
    }
    __syncthreads();

    if (threadIdx.x == 0) {
        double bsum = s_sum[0], bsum0 = s_sum0[0];
        int bcnt = s_cnt[0];
        float bmn = s_mn[0], bmx = s_mx[0];
        #pragma unroll
        for (int w = 1; w < BS / 64; ++w) {
            bsum += s_sum[w]; bsum0 += s_sum0[w]; bcnt += s_cnt[w];
            bmn = fminf(bmn, s_mn[w]); bmx = fmaxf(bmx, s_mx[w]);
        }
        ws[0 * NB1 + blockIdx.x] = bsum;
        ws[1 * NB1 + blockIdx.x] = bsum0;
        ws[2 * NB1 + blockIdx.x] = (double)bcnt;
        ws[3 * NB1 + blockIdx.x] = (double)bmn;
        ws[4 * NB1 + blockIdx.x] = (double)bmx;
    }
}

__global__ __launch_bounds__(P2BS) void risk_pass2(const double* __restrict__ ws,
                                                   float* __restrict__ out,
                                                   long long n_total) {
    double sum = 0.0, sum0 = 0.0, cnt0 = 0.0;
    double mn =  INFINITY;
    double mx = -INFINITY;

    for (int i = threadIdx.x; i < NB1; i += P2BS) {
        sum  += ws[0 * NB1 + i];
        sum0 += ws[1 * NB1 + i];
        cnt0 += ws[2 * NB1 + i];
        mn = fmin(mn, ws[3 * NB1 + i]);
        mx = fmax(mx, ws[4 * NB1 + i]);
    }

    for (int off = 32; off > 0; off >>= 1) {
        sum  += __shfl_down(sum,  off);
        sum0 += __shfl_down(sum0, off);
        cnt0 += __shfl_down(cnt0, off);
        mn = fmin(mn, __shfl_down(mn, off));
        mx = fmax(mx, __shfl_down(mx, off));
    }

    __shared__ double s_sum[P2BS / 64], s_sum0[P2BS / 64], s_cnt[P2BS / 64];
    __shared__ double s_mn[P2BS / 64], s_mx[P2BS / 64];
    int lane = threadIdx.x & 63;
    int wave = threadIdx.x >> 6;
    if (lane == 0) {
        s_sum[wave] = sum; s_sum0[wave] = sum0; s_cnt[wave] = cnt0;
        s_mn[wave] = mn; s_mx[wave] = mx;
    }
    __syncthreads();

    if (threadIdx.x == 0) {
        double tsum = s_sum[0], tsum0 = s_sum0[0], tcnt0 = s_cnt[0];
        double tmn = s_mn[0], tmx = s_mx[0];
        #pragma unroll
        for (int w = 1; w < P2BS / 64; ++w) {
            tsum += s_sum[w]; tsum0 += s_sum0[w]; tcnt0 += s_cnt[w];
            tmn = fmin(tmn, s_mn[w]); tmx = fmax(tmx, s_mx[w]);
        }
        double range = tmx - tmn;
        double n1 = (double)n_total - tcnt0;
        double sum1 = tsum - tsum0;
        double m0 = (tsum0 / tcnt0 - tmn) / range;
        double m1 = (sum1  / n1    - tmn) / range;
        double l = fmin(m0, m1) - fmax(m0, m1);  // = -|m0 - m1|
        out[0] = (float)l;
    }
}

extern "C" void kernel_launch(void* const* d_in, const int* in_sizes, int n_in,
                              void* d_out, int out_size, void* d_ws, size_t ws_size,
                              hipStream_t stream) {
    const float* x = (const float*)d_in[0];
    const int*   y = (const int*)d_in[1];
    float* out = (float*)d_out;
    double* ws = (double*)d_ws;
    long long n = (long long)in_sizes[0];  // 33554432 == NB1*BS*LQ*NBATCH*4

    risk_pass1<<<NB1, BS, 0, stream>>>(x, y, ws);
    risk_pass2<<<1, P2BS, 0, stream>>>(ws, out, n);
}